// Round 7
// baseline (186.630 us; speedup 1.0000x reference)
//
#include <hip/hip_runtime.h>
#include <math.h>

#define SEQ   2048
#define HDIM  1024
#define NH    16
#define DH    64
#define MTOT  4096   // B*S
#define BHTOT 32     // B*NH

typedef _Float16 half_t;
typedef __attribute__((ext_vector_type(2))) __fp16 fp16x2;
typedef __attribute__((ext_vector_type(4))) _Float16 half4;
typedef __attribute__((ext_vector_type(8))) _Float16 half8;
typedef __attribute__((ext_vector_type(4))) float float4v;

// async global->LDS DMA, 16 B per lane; LDS dest = wave-uniform base + lane*16
typedef __attribute__((address_space(1))) const unsigned int guint;
typedef __attribute__((address_space(3))) unsigned int luint;
__device__ __forceinline__ void glds16(const half_t* g, half_t* l) {
    __builtin_amdgcn_global_load_lds((guint*)g, (luint*)l, 16, 0, 0);
}

// ---------------- fused prologue: 5 fp32->fp16 casts + rope table ----------------
__global__ __launch_bounds__(256)
void prep(const float* __restrict__ x,  const float* __restrict__ wq,
          const float* __restrict__ wk, const float* __restrict__ wv,
          const float* __restrict__ wo,
          half_t* __restrict__ xh,  half_t* __restrict__ wqh,
          half_t* __restrict__ wkh, half_t* __restrict__ wvh,
          half_t* __restrict__ woh, float2* __restrict__ rope)
{
    const int bid = blockIdx.x;
    if (bid < 8192) {
        int i = bid * 256 + threadIdx.x;
        const float* s; half_t* d;
        if (i < 1048576) { s = x; d = xh; }
        else {
            int j = i - 1048576;
            int w = j >> 18; i = j & 262143;
            s = (w == 0) ? wq : (w == 1) ? wk : (w == 2) ? wv : wo;
            d = (w == 0) ? wqh : (w == 1) ? wkh : (w == 2) ? wvh : woh;
        }
        float4 v = ((const float4*)s)[i];
        union { half_t h[4]; uint2 u; } tmp;
        tmp.h[0] = (half_t)v.x; tmp.h[1] = (half_t)v.y;
        tmp.h[2] = (half_t)v.z; tmp.h[3] = (half_t)v.w;
        ((uint2*)d)[i] = tmp.u;
    } else {
        int tt = (bid - 8192) * 256 + threadIdx.x;   // 0 .. SEQ*32-1
        int s = tt >> 5, j = tt & 31;
        float inv = powf(10000.0f, -(float)j / 32.0f);
        float ang = (float)s * inv;
        rope[tt] = make_float2(cosf(ang), sinf(ang));
    }
}

// ---------------- GEMM: QKV only. C = A(4096x1024,f16) * W^T, 128x128 tiles ----
// BK=64, line-local XOR swizzle, 5 blocks/CU. (unchanged — verified)
__global__ __launch_bounds__(256, 5)
void gemm_qkv(const half_t* __restrict__ A,
              const half_t* __restrict__ w0, const half_t* __restrict__ w1,
              const half_t* __restrict__ w2,
              half_t* __restrict__ Qb, half_t* __restrict__ Kb,
              half_t* __restrict__ Vtb,
              const float2* __restrict__ rope)
{
    const int mode = blockIdx.z;
    const half_t* Bw = (mode == 1) ? w1 : (mode == 2) ? w2 : w0;

    __shared__ __align__(16) half_t Tsh[2][128][64];   // A tile | B tile, 32 KB
    half_t (*Ash)[64] = Tsh[0];
    half_t (*Bsh)[64] = Tsh[1];

    const int t    = threadIdx.x;
    const int lane = t & 63;
    const int wave = t >> 6;
    const int quad = lane >> 4;
    const int l16  = lane & 15;
    const int wr   = (wave >> 1) * 64;
    const int wc   = (wave & 1) * 64;
    const int bm   = blockIdx.x, bn = blockIdx.y;

    const int srow   = lane >> 3;               // 0..7 within an 8-row DMA chunk
    const int schunk = (lane & 7) ^ (srow & 3); // line-local pre-swizzle
    const half_t* Asrc = A  + (size_t)(bm * 128 + srow) * HDIM + schunk * 8;
    const half_t* Bsrc = Bw + (size_t)(bn * 128 + srow) * HDIM + schunk * 8;
    const int swz = (l16 & 3) << 4;             // read-side XOR (byte offset)

    float4v acc[4][4] = {};

    for (int kt = 0; kt < HDIM / 64; ++kt) {
        const half_t* Ak = Asrc + kt * 64;
        const half_t* Bk = Bsrc + kt * 64;
#pragma unroll
        for (int c = 0; c < 4; ++c) {
            const int r8 = wave * 32 + c * 8;
            glds16(Ak + (size_t)r8 * HDIM, &Ash[r8][0]);
            glds16(Bk + (size_t)r8 * HDIM, &Bsh[r8][0]);
        }
        __syncthreads();
#pragma unroll
        for (int kk = 0; kk < 2; ++kk) {
            const int cb = ((quad << 4) | (kk << 6)) ^ swz;
            half8 af[4], bf[4];
#pragma unroll
            for (int mb = 0; mb < 4; ++mb)
                af[mb] = *(const half8*)((const char*)&Ash[wr + mb * 16 + l16][0] + cb);
#pragma unroll
            for (int nb = 0; nb < 4; ++nb)
                bf[nb] = *(const half8*)((const char*)&Bsh[wc + nb * 16 + l16][0] + cb);
#pragma unroll
            for (int mb = 0; mb < 4; ++mb)
#pragma unroll
                for (int nb = 0; nb < 4; ++nb)
                    acc[mb][nb] = __builtin_amdgcn_mfma_f32_16x16x32_f16(af[mb], bf[nb], acc[mb][nb], 0, 0, 0);
        }
        __syncthreads();
    }

    if (mode == 2) {  // V, transposed store: Vtb[bh][d][s]
#pragma unroll
        for (int mb = 0; mb < 4; ++mb)
#pragma unroll
            for (int nb = 0; nb < 4; ++nb) {
                int row0 = bm * 128 + wr + mb * 16 + quad * 4;
                int col  = bn * 128 + wc + nb * 16 + l16;
                int b = row0 >> 11, s0 = row0 & 2047;
                int h = col >> 6,  dd = col & 63;
                union { half_t h4[4]; uint2 u; } tmp;
#pragma unroll
                for (int r = 0; r < 4; ++r) tmp.h4[r] = (half_t)acc[mb][nb][r];
                *(uint2*)&Vtb[((size_t)((b * NH + h) * DH + dd)) * SEQ + s0] = tmp.u;
            }
        return;
    }
    // mode 0 (Q: rope + scale) / mode 1 (K: rope)
    {
        half_t* Ob = (mode == 0) ? Qb : Kb;
        const float scl = (mode == 0) ? 0.125f * 1.44269504088896f : 1.0f;
        const int h = (bn * 128 + wc) >> 6;   // wave's 64 cols = one head
        float* E = (float*)&Tsh[0][0][0] + wave * 1088;
#pragma unroll
        for (int mb = 0; mb < 4; ++mb) {
#pragma unroll
            for (int nb = 0; nb < 4; ++nb)
#pragma unroll
                for (int r = 0; r < 4; ++r)
                    E[(quad * 4 + r) * 68 + nb * 16 + l16] = acc[mb][nb][r];
            __asm__ volatile("s_waitcnt lgkmcnt(0)" ::: "memory");  // wave-private region
#pragma unroll
            for (int c = 0; c < 2; ++c) {
                const int uidx = c * 64 + lane;
                const int row = uidx >> 3, ch = uidx & 7;
                const int sg = bm * 128 + wr + mb * 16 + row;
                const int b = sg >> 11, s = sg & 2047;
                const float* Er = E + row * 68 + ch * 8;
                const float4 e0 = *(const float4*)Er;
                const float4 e1 = *(const float4*)(Er + 4);
                const float4* rp = (const float4*)(rope + (size_t)s * 32 + ch * 4);
                const float4 r01 = rp[0];   // cos0,sin0,cos1,sin1
                const float4 r23 = rp[1];
                union { half_t hh[8]; uint4 u; } o;
                o.hh[0] = (half_t)((e0.x * r01.x - e0.y * r01.y) * scl);
                o.hh[1] = (half_t)((e0.x * r01.y + e0.y * r01.x) * scl);
                o.hh[2] = (half_t)((e0.z * r01.z - e0.w * r01.w) * scl);
                o.hh[3] = (half_t)((e0.z * r01.w + e0.w * r01.z) * scl);
                o.hh[4] = (half_t)((e1.x * r23.x - e1.y * r23.y) * scl);
                o.hh[5] = (half_t)((e1.x * r23.y + e1.y * r23.x) * scl);
                o.hh[6] = (half_t)((e1.z * r23.z - e1.w * r23.w) * scl);
                o.hh[7] = (half_t)((e1.z * r23.w + e1.w * r23.z) * scl);
                *(uint4*)&Ob[((size_t)((b * NH + h) * SEQ + s)) * DH + ch * 8] = o.u;
            }
        }
    }
}

// ---------------- output GEMM: out(f32) = ah(4096x1024,f16) @ wo^T ----------------
// 64x64 tiles -> grid (64,16) = 1024 blocks = 4 blocks/CU, 2-phase prefetch.
__global__ __launch_bounds__(256)
void gemm_out(const half_t* __restrict__ A, const half_t* __restrict__ W,
              float* __restrict__ outF)
{
    __shared__ __align__(16) half_t Ash[2][64][64];    // 16 KB
    __shared__ __align__(16) half_t Bsh[2][64][64];    // 16 KB

    const int t    = threadIdx.x;
    const int lane = t & 63;
    const int wave = t >> 6;
    const int quad = lane >> 4;
    const int l16  = lane & 15;
    const int wr   = (wave >> 1) * 32;   // M offset within tile
    const int wc   = (wave & 1) * 32;    // N offset
    const int bm   = blockIdx.x, bn = blockIdx.y;

    const int srow   = lane >> 3;
    const int schunk = (lane & 7) ^ (srow & 3);
    const half_t* Asrc = A + (size_t)(bm * 64 + srow) * HDIM + schunk * 8;
    const half_t* Bsrc = W + (size_t)(bn * 64 + srow) * HDIM + schunk * 8;
    const int swz = (l16 & 3) << 4;

    auto stage = [&](int kt, int buf) {
        const half_t* Ak = Asrc + kt * 64;
        const half_t* Bk = Bsrc + kt * 64;
#pragma unroll
        for (int c = 0; c < 2; ++c) {
            const int r8 = wave * 16 + c * 8;
            glds16(Ak + (size_t)r8 * HDIM, &Ash[buf][r8][0]);
            glds16(Bk + (size_t)r8 * HDIM, &Bsh[buf][r8][0]);
        }
    };

    float4v acc[2][2] = {};

    stage(0, 0);
    __asm__ volatile("s_waitcnt vmcnt(0)" ::: "memory");
    __builtin_amdgcn_s_barrier();
    __builtin_amdgcn_sched_barrier(0);

    for (int kt = 0; kt < HDIM / 64; ++kt) {
        const int cur = kt & 1, nxt = cur ^ 1;
        if (kt + 1 < HDIM / 64) stage(kt + 1, nxt);   // prefetch under compute
#pragma unroll
        for (int kk = 0; kk < 2; ++kk) {
            const int cb = ((quad << 4) | (kk << 6)) ^ swz;
            half8 af[2], bf[2];
#pragma unroll
            for (int mb = 0; mb < 2; ++mb)
                af[mb] = *(const half8*)((const char*)&Ash[cur][wr + mb * 16 + l16][0] + cb);
#pragma unroll
            for (int nb = 0; nb < 2; ++nb)
                bf[nb] = *(const half8*)((const char*)&Bsh[cur][wc + nb * 16 + l16][0] + cb);
#pragma unroll
            for (int mb = 0; mb < 2; ++mb)
#pragma unroll
                for (int nb = 0; nb < 2; ++nb)
                    acc[mb][nb] = __builtin_amdgcn_mfma_f32_16x16x32_f16(af[mb], bf[nb], acc[mb][nb], 0, 0, 0);
        }
        __asm__ volatile("s_waitcnt vmcnt(0)" ::: "memory");  // next tile landed
        __builtin_amdgcn_s_barrier();
        __builtin_amdgcn_sched_barrier(0);
    }

#pragma unroll
    for (int mb = 0; mb < 2; ++mb)
#pragma unroll
        for (int nb = 0; nb < 2; ++nb) {
            int row0 = bm * 64 + wr + mb * 16 + quad * 4;
            int col  = bn * 64 + wc + nb * 16 + l16;
#pragma unroll
            for (int r = 0; r < 4; ++r)
                outF[(size_t)(row0 + r) * HDIM + col] = acc[mb][nb][r];
        }
}

// ---------------- fused attention ----------------
// Reference semantics: softmax over ALL keys, THEN causal zeroing, NO renorm.
// v7: 128-key iterations — HALVES the per-tile sync cost (vmcnt/lgkm drain +
// 8-wave barrier), the residual that depth-2 prefetch (r5) and cross-iter
// pipelining (r6) could not remove. Ksh[2][128][64] + Vsh[2][64][128] dbuf
// (64 KB, 2 blocks/CU = 16 waves/CU). Per iteration: stage K(T+1) (2 glds16/
// wave) + V(T+1) (2 uint4/thread, issue-early/write-late), then two
// independent 64-key half-chains {QK->exp->cvt->PV} give intra-iteration ILP
// between barriers. Compute/iter (~2500cy) >> DMA latency -> plain vmcnt(0)
// at iter end is nearly free. V 16-chunk XOR swizzle (chunk^(d&15), both
// sides): PV reads 2-way bank = free.
__global__ __launch_bounds__(512, 4)
void attn_fused(const half_t* __restrict__ Qb, const half_t* __restrict__ Kb,
                const half_t* __restrict__ Vtb, half_t* __restrict__ AOut)
{
    const int bx = blockIdx.x;   // 0..15
    const int p  = bx >> 1;      // q-tile pair (p, 15-p), p in 0..7
    const int hf = bx & 1;       // which 64-row half of each tile
    const int bh = blockIdx.y;   // 0..31 (b*16+h)
    const int NT = SEQ / 128;    // 16 iterations of 128 keys

    __shared__ __align__(16) half_t Ksh[2][128][64];   // [buf][key][d], 32 KB
    __shared__ __align__(16) half_t Vsh[2][64][128];   // [buf][d][key], 32 KB

    const int t = threadIdx.x;
    const int wave = t >> 6, lane = t & 63, quad = lane >> 4, l16 = lane & 15;
    const int heavy = wave >> 2, wl = wave & 3;
    const int qtile = heavy ? (15 - p) : p;
    const int q0 = qtile * 128 + hf * 64 + wl * 16;   // wave's 16 q rows
    const int vtop = 15 - p;    // last V tile needed by this block (128-key units)

    // Q fragment (B-operand layout of 16x16x32)
    const half_t* Qp = Qb + ((size_t)bh * SEQ + q0 + l16) * DH + quad * 8;
    const half8 qf0 = *(const half8*)Qp;
    const half8 qf1 = *(const half8*)(Qp + 32);

    float4v o[4] = {};     // O^T accum
    float4v ls = {};       // 4 independent denominator chains

    // K DMA staging: wave stages rows wave*16 .. wave*16+15 (two 8-row chunks,
    // XOR chunk swizzle within each 8-row group)
    const int krow = lane >> 3, kpos = lane & 7;
    const int kchunk = kpos ^ krow;
    const half_t* Ksrc = Kb + ((size_t)bh * SEQ + wave * 16 + krow) * DH + kchunk * 8;
    const int ko1 = ((quad ^ (l16 & 7)) * 8);
    const int ko2 = ko1 ^ 32;

    // V staging: 512 threads x 2 uint4 = 64 x 128 tile; 16-chunk XOR swizzle
    const int sr  = t >> 3;          // d: 0..63
    const int sc0 = t & 7;           // chunks sc0 and sc0+8 (8 halfs each)
    const half_t* Vg = Vtb + ((size_t)bh * DH + sr) * SEQ + sc0 * 8;
    const int vso0 = ((sc0    ) ^ (sr & 15)) * 8;   // swizzled store offsets (halfs)
    const int vso1 = ((sc0 + 8) ^ (sr & 15)) * 8;

    // ---- prologue: stage K(0), V(0) ----
    {
        uint4 va0 = *(const uint4*)(Vg);
        uint4 va1 = *(const uint4*)(Vg + 64);
        glds16(Ksrc,          &Ksh[0][wave * 16][0]);
        glds16(Ksrc + 8 * DH, &Ksh[0][wave * 16 + 8][0]);
        *(uint4*)&Vsh[0][sr][vso0] = va0;
        *(uint4*)&Vsh[0][sr][vso1] = va1;
    }
    __asm__ volatile("s_waitcnt vmcnt(0)" ::: "memory");
    __asm__ volatile("s_waitcnt lgkmcnt(0)" ::: "memory");
    __builtin_amdgcn_s_barrier();
    __builtin_amdgcn_sched_barrier(0);

    for (int T = 0; T < NT; ++T) {
        const int cur = T & 1, nxt = cur ^ 1;
        const bool kn = (T + 1 < NT);
        const bool vn = kn && (T + 1 <= vtop);

        uint4 va0, va1;
        if (vn) {                         // issue-early
            va0 = *(const uint4*)(Vg + (T + 1) * 128);
            va1 = *(const uint4*)(Vg + (T + 1) * 128 + 64);
        }
        if (kn) {
            const half_t* Kn = Ksrc + (size_t)(T + 1) * 128 * DH;
            glds16(Kn,          &Ksh[nxt][wave * 16][0]);
            glds16(Kn + 8 * DH, &Ksh[nxt][wave * 16 + 8][0]);
        }

#pragma unroll
        for (int hh = 0; hh < 2; ++hh) {
            // S^T = K * Q^T over this 64-key half
            float4v sc[4];
            __builtin_amdgcn_s_setprio(1);
#pragma unroll
            for (int nb = 0; nb < 4; ++nb) {
                const half_t* kp = &Ksh[cur][hh * 64 + nb * 16 + l16][0];
                half8 kf0 = *(const half8*)(kp + ko1);
                half8 kf1 = *(const half8*)(kp + ko2);
                float4v a = {};
                a = __builtin_amdgcn_mfma_f32_16x16x32_f16(kf0, qf0, a, 0, 0, 0);
                a = __builtin_amdgcn_mfma_f32_16x16x32_f16(kf1, qf1, a, 0, 0, 0);
                sc[nb] = a;
            }
            __builtin_amdgcn_s_setprio(0);

            // P = exp2(sc); 4 independent partial-denominator chains
#pragma unroll
            for (int nb = 0; nb < 4; ++nb)
#pragma unroll
                for (int r = 0; r < 4; ++r) {
                    float e = __builtin_amdgcn_exp2f(sc[nb][r]);
                    sc[nb][r] = e;
                    ls[r] += e;
                }

            const int kbase = T * 128 + hh * 64;
            if (kbase <= q0 + 15) {   // wave-uniform: at least one unmasked key
                if (kbase + 63 > q0) {   // straddle: post-softmax zeroing
                    int qg = q0 + l16;
#pragma unroll
                    for (int nb = 0; nb < 4; ++nb)
#pragma unroll
                        for (int r = 0; r < 4; ++r)
                            if (kbase + nb * 16 + quad * 4 + r > qg) sc[nb][r] = 0.f;
                }
                half4 pf[4];
#pragma unroll
                for (int nb = 0; nb < 4; ++nb) {
                    union { fp16x2 v2[2]; half4 v4; } u;
                    u.v2[0] = __builtin_amdgcn_cvt_pkrtz(sc[nb][0], sc[nb][1]);
                    u.v2[1] = __builtin_amdgcn_cvt_pkrtz(sc[nb][2], sc[nb][3]);
                    pf[nb] = u.v4;
                }
                __builtin_amdgcn_s_setprio(1);
#pragma unroll
                for (int md = 0; md < 4; ++md) {
                    const char* vrow = (const char*)&Vsh[cur][md * 16 + l16][0];
#pragma unroll
                    for (int nb = 0; nb < 4; ++nb) {
                        const int chunk = (hh * 8 + nb * 2 + (quad >> 1)) ^ l16;
                        half4 vf = *(const half4*)(vrow + chunk * 16 + (quad & 1) * 8);
                        o[md] = __builtin_amdgcn_mfma_f32_16x16x16f16(vf, pf[nb], o[md], 0, 0, 0);
                    }
                }
                __builtin_amdgcn_s_setprio(0);
            }
        }

        if (vn) {                         // write-late into the other buffer
            *(uint4*)&Vsh[nxt][sr][vso0] = va0;
            *(uint4*)&Vsh[nxt][sr][vso1] = va1;
        }
        __asm__ volatile("s_waitcnt vmcnt(0)" ::: "memory");
        __asm__ volatile("s_waitcnt lgkmcnt(0)" ::: "memory");
        __builtin_amdgcn_s_barrier();
        __builtin_amdgcn_sched_barrier(0);
    }

    // epilogue: denominator (2 shuffles) + O^T transpose via per-wave LDS scratch.
    const int b = bh >> 4, h = bh & 15;
    const int orow = lane >> 2, occ = (lane & 3) * 16;
    half_t* scr = (heavy ? (half_t*)Vsh : (half_t*)Ksh) + wl * 1152;
    half_t (*Osh)[72] = (half_t(*)[72])scr;   // 16 x 72
    {
        float rs = (ls[0] + ls[1]) + (ls[2] + ls[3]);
        rs += __shfl_xor(rs, 16, 64);
        rs += __shfl_xor(rs, 32, 64);
        const float inv = 1.0f / rs;
#pragma unroll
        for (int md = 0; md < 4; ++md)
#pragma unroll
            for (int r = 0; r < 4; ++r)
                Osh[l16][md * 16 + quad * 4 + r] = (half_t)(o[md][r] * inv);
        __asm__ volatile("s_waitcnt lgkmcnt(0)" ::: "memory");
        uint4 o0 = *(const uint4*)&Osh[orow][occ];
        uint4 o1 = *(const uint4*)&Osh[orow][occ + 8];
        const int s = q0 + orow;
        half_t* dst = AOut + ((size_t)(b * SEQ + s)) * HDIM + h * DH + occ;
        *(uint4*)dst       = o0;
        *(uint4*)(dst + 8) = o1;
    }
}

// ---------------- launch ----------------
extern "C" void kernel_launch(void* const* d_in, const int* in_sizes, int n_in,
                              void* d_out, int out_size, void* d_ws, size_t ws_size,
                              hipStream_t stream)
{
    const float* x  = (const float*)d_in[0];
    const float* wq = (const float*)d_in[1];
    const float* wk = (const float*)d_in[2];
    const float* wv = (const float*)d_in[3];
    const float* wo = (const float*)d_in[4];
    float* out = (float*)d_out;

    char* ws = (char*)d_ws;
    size_t off = 0;
    auto alloc = [&](size_t bytes) -> void* {
        void* p = ws + off;
        off += (bytes + 255) & ~(size_t)255;
        return p;
    };
    half_t* xh   = (half_t*)alloc((size_t)MTOT * HDIM * 2);   // 8 MB
    half_t* wqh  = (half_t*)alloc((size_t)HDIM * HDIM * 2);   // 2 MB
    half_t* wkh  = (half_t*)alloc((size_t)HDIM * HDIM * 2);
    half_t* wvh  = (half_t*)alloc((size_t)HDIM * HDIM * 2);
    half_t* woh  = (half_t*)alloc((size_t)HDIM * HDIM * 2);
    half_t* Qb   = (half_t*)alloc((size_t)BHTOT * SEQ * DH * 2);  // 8 MB
    half_t* Kb   = (half_t*)alloc((size_t)BHTOT * SEQ * DH * 2);
    half_t* Vtb  = (half_t*)alloc((size_t)BHTOT * SEQ * DH * 2);
    half_t* ah   = (half_t*)alloc((size_t)MTOT * HDIM * 2);       // 8 MB
    float2* rope = (float2*)alloc((size_t)SEQ * 32 * sizeof(float2));

    prep<<<8448, 256, 0, stream>>>(x, wq, wk, wv, wo, xh, wqh, wkh, wvh, woh, rope);

    // Q, K, V in one launch (grid.z selects weight + epilogue)
    gemm_qkv<<<dim3(32, 8, 3), 256, 0, stream>>>(xh, wqh, wkh, wvh,
                                                 Qb, Kb, Vtb, rope);
    // attn: 512-thread blocks, 512 blocks = 2 blocks/CU, 128-key iterations
    attn_fused<<<dim3(16, 32), 512, 0, stream>>>(Qb, Kb, Vtb, ah);
    // out = attn @ w_o^T: 64x64 tiles, 1024 blocks = 4 blocks/CU, 2-phase
    gemm_out<<<dim3(64, 16), 256, 0, stream>>>(ah, woh, out);
}

// Round 8
// 186.218 us; speedup vs baseline: 1.0022x; 1.0022x over previous
//
#include <hip/hip_runtime.h>
#include <math.h>

#define SEQ   2048
#define HDIM  1024
#define NH    16
#define DH    64
#define MTOT  4096   // B*S
#define BHTOT 32     // B*NH

typedef _Float16 half_t;
typedef __attribute__((ext_vector_type(2))) __fp16 fp16x2;
typedef __attribute__((ext_vector_type(4))) _Float16 half4;
typedef __attribute__((ext_vector_type(8))) _Float16 half8;
typedef __attribute__((ext_vector_type(4))) float float4v;

// async global->LDS DMA, 16 B per lane; LDS dest = wave-uniform base + lane*16
typedef __attribute__((address_space(1))) const unsigned int guint;
typedef __attribute__((address_space(3))) unsigned int luint;
__device__ __forceinline__ void glds16(const half_t* g, half_t* l) {
    __builtin_amdgcn_global_load_lds((guint*)g, (luint*)l, 16, 0, 0);
}

// ---------------- fused prologue: 5 fp32->fp16 casts + rope table ----------------
__global__ __launch_bounds__(256)
void prep(const float* __restrict__ x,  const float* __restrict__ wq,
          const float* __restrict__ wk, const float* __restrict__ wv,
          const float* __restrict__ wo,
          half_t* __restrict__ xh,  half_t* __restrict__ wqh,
          half_t* __restrict__ wkh, half_t* __restrict__ wvh,
          half_t* __restrict__ woh, float2* __restrict__ rope)
{
    const int bid = blockIdx.x;
    if (bid < 8192) {
        int i = bid * 256 + threadIdx.x;
        const float* s; half_t* d;
        if (i < 1048576) { s = x; d = xh; }
        else {
            int j = i - 1048576;
            int w = j >> 18; i = j & 262143;
            s = (w == 0) ? wq : (w == 1) ? wk : (w == 2) ? wv : wo;
            d = (w == 0) ? wqh : (w == 1) ? wkh : (w == 2) ? wvh : woh;
        }
        float4 v = ((const float4*)s)[i];
        union { half_t h[4]; uint2 u; } tmp;
        tmp.h[0] = (half_t)v.x; tmp.h[1] = (half_t)v.y;
        tmp.h[2] = (half_t)v.z; tmp.h[3] = (half_t)v.w;
        ((uint2*)d)[i] = tmp.u;
    } else {
        int tt = (bid - 8192) * 256 + threadIdx.x;   // 0 .. SEQ*32-1
        int s = tt >> 5, j = tt & 31;
        float inv = powf(10000.0f, -(float)j / 32.0f);
        float ang = (float)s * inv;
        rope[tt] = make_float2(cosf(ang), sinf(ang));
    }
}

// ---------------- GEMM: QKV only. C = A(4096x1024,f16) * W^T, 128x128 tiles ----
// BK=64, line-local XOR swizzle, 5 blocks/CU. (unchanged — verified)
__global__ __launch_bounds__(256, 5)
void gemm_qkv(const half_t* __restrict__ A,
              const half_t* __restrict__ w0, const half_t* __restrict__ w1,
              const half_t* __restrict__ w2,
              half_t* __restrict__ Qb, half_t* __restrict__ Kb,
              half_t* __restrict__ Vtb,
              const float2* __restrict__ rope)
{
    const int mode = blockIdx.z;
    const half_t* Bw = (mode == 1) ? w1 : (mode == 2) ? w2 : w0;

    __shared__ __align__(16) half_t Tsh[2][128][64];   // A tile | B tile, 32 KB
    half_t (*Ash)[64] = Tsh[0];
    half_t (*Bsh)[64] = Tsh[1];

    const int t    = threadIdx.x;
    const int lane = t & 63;
    const int wave = t >> 6;
    const int quad = lane >> 4;
    const int l16  = lane & 15;
    const int wr   = (wave >> 1) * 64;
    const int wc   = (wave & 1) * 64;
    const int bm   = blockIdx.x, bn = blockIdx.y;

    const int srow   = lane >> 3;               // 0..7 within an 8-row DMA chunk
    const int schunk = (lane & 7) ^ (srow & 3); // line-local pre-swizzle
    const half_t* Asrc = A  + (size_t)(bm * 128 + srow) * HDIM + schunk * 8;
    const half_t* Bsrc = Bw + (size_t)(bn * 128 + srow) * HDIM + schunk * 8;
    const int swz = (l16 & 3) << 4;             // read-side XOR (byte offset)

    float4v acc[4][4] = {};

    for (int kt = 0; kt < HDIM / 64; ++kt) {
        const half_t* Ak = Asrc + kt * 64;
        const half_t* Bk = Bsrc + kt * 64;
#pragma unroll
        for (int c = 0; c < 4; ++c) {
            const int r8 = wave * 32 + c * 8;
            glds16(Ak + (size_t)r8 * HDIM, &Ash[r8][0]);
            glds16(Bk + (size_t)r8 * HDIM, &Bsh[r8][0]);
        }
        __syncthreads();
#pragma unroll
        for (int kk = 0; kk < 2; ++kk) {
            const int cb = ((quad << 4) | (kk << 6)) ^ swz;
            half8 af[4], bf[4];
#pragma unroll
            for (int mb = 0; mb < 4; ++mb)
                af[mb] = *(const half8*)((const char*)&Ash[wr + mb * 16 + l16][0] + cb);
#pragma unroll
            for (int nb = 0; nb < 4; ++nb)
                bf[nb] = *(const half8*)((const char*)&Bsh[wc + nb * 16 + l16][0] + cb);
#pragma unroll
            for (int mb = 0; mb < 4; ++mb)
#pragma unroll
                for (int nb = 0; nb < 4; ++nb)
                    acc[mb][nb] = __builtin_amdgcn_mfma_f32_16x16x32_f16(af[mb], bf[nb], acc[mb][nb], 0, 0, 0);
        }
        __syncthreads();
    }

    if (mode == 2) {  // V, transposed store: Vtb[bh][d][s]
#pragma unroll
        for (int mb = 0; mb < 4; ++mb)
#pragma unroll
            for (int nb = 0; nb < 4; ++nb) {
                int row0 = bm * 128 + wr + mb * 16 + quad * 4;
                int col  = bn * 128 + wc + nb * 16 + l16;
                int b = row0 >> 11, s0 = row0 & 2047;
                int h = col >> 6,  dd = col & 63;
                union { half_t h4[4]; uint2 u; } tmp;
#pragma unroll
                for (int r = 0; r < 4; ++r) tmp.h4[r] = (half_t)acc[mb][nb][r];
                *(uint2*)&Vtb[((size_t)((b * NH + h) * DH + dd)) * SEQ + s0] = tmp.u;
            }
        return;
    }
    // mode 0 (Q: rope + scale) / mode 1 (K: rope)
    {
        half_t* Ob = (mode == 0) ? Qb : Kb;
        const float scl = (mode == 0) ? 0.125f * 1.44269504088896f : 1.0f;
        const int h = (bn * 128 + wc) >> 6;   // wave's 64 cols = one head
        float* E = (float*)&Tsh[0][0][0] + wave * 1088;
#pragma unroll
        for (int mb = 0; mb < 4; ++mb) {
#pragma unroll
            for (int nb = 0; nb < 4; ++nb)
#pragma unroll
                for (int r = 0; r < 4; ++r)
                    E[(quad * 4 + r) * 68 + nb * 16 + l16] = acc[mb][nb][r];
            __asm__ volatile("s_waitcnt lgkmcnt(0)" ::: "memory");  // wave-private region
#pragma unroll
            for (int c = 0; c < 2; ++c) {
                const int uidx = c * 64 + lane;
                const int row = uidx >> 3, ch = uidx & 7;
                const int sg = bm * 128 + wr + mb * 16 + row;
                const int b = sg >> 11, s = sg & 2047;
                const float* Er = E + row * 68 + ch * 8;
                const float4 e0 = *(const float4*)Er;
                const float4 e1 = *(const float4*)(Er + 4);
                const float4* rp = (const float4*)(rope + (size_t)s * 32 + ch * 4);
                const float4 r01 = rp[0];   // cos0,sin0,cos1,sin1
                const float4 r23 = rp[1];
                union { half_t hh[8]; uint4 u; } o;
                o.hh[0] = (half_t)((e0.x * r01.x - e0.y * r01.y) * scl);
                o.hh[1] = (half_t)((e0.x * r01.y + e0.y * r01.x) * scl);
                o.hh[2] = (half_t)((e0.z * r01.z - e0.w * r01.w) * scl);
                o.hh[3] = (half_t)((e0.z * r01.w + e0.w * r01.z) * scl);
                o.hh[4] = (half_t)((e1.x * r23.x - e1.y * r23.y) * scl);
                o.hh[5] = (half_t)((e1.x * r23.y + e1.y * r23.x) * scl);
                o.hh[6] = (half_t)((e1.z * r23.z - e1.w * r23.w) * scl);
                o.hh[7] = (half_t)((e1.z * r23.w + e1.w * r23.z) * scl);
                *(uint4*)&Ob[((size_t)((b * NH + h) * SEQ + s)) * DH + ch * 8] = o.u;
            }
        }
    }
}

// ---------------- output GEMM: out(f32) = ah(4096x1024,f16) @ wo^T ----------------
// 64x64 tiles -> grid (64,16) = 1024 blocks = 4 blocks/CU, 2-phase prefetch.
__global__ __launch_bounds__(256)
void gemm_out(const half_t* __restrict__ A, const half_t* __restrict__ W,
              float* __restrict__ outF)
{
    __shared__ __align__(16) half_t Ash[2][64][64];    // 16 KB
    __shared__ __align__(16) half_t Bsh[2][64][64];    // 16 KB

    const int t    = threadIdx.x;
    const int lane = t & 63;
    const int wave = t >> 6;
    const int quad = lane >> 4;
    const int l16  = lane & 15;
    const int wr   = (wave >> 1) * 32;   // M offset within tile
    const int wc   = (wave & 1) * 32;    // N offset
    const int bm   = blockIdx.x, bn = blockIdx.y;

    const int srow   = lane >> 3;
    const int schunk = (lane & 7) ^ (srow & 3);
    const half_t* Asrc = A + (size_t)(bm * 64 + srow) * HDIM + schunk * 8;
    const half_t* Bsrc = W + (size_t)(bn * 64 + srow) * HDIM + schunk * 8;
    const int swz = (l16 & 3) << 4;

    auto stage = [&](int kt, int buf) {
        const half_t* Ak = Asrc + kt * 64;
        const half_t* Bk = Bsrc + kt * 64;
#pragma unroll
        for (int c = 0; c < 2; ++c) {
            const int r8 = wave * 16 + c * 8;
            glds16(Ak + (size_t)r8 * HDIM, &Ash[buf][r8][0]);
            glds16(Bk + (size_t)r8 * HDIM, &Bsh[buf][r8][0]);
        }
    };

    float4v acc[2][2] = {};

    stage(0, 0);
    __asm__ volatile("s_waitcnt vmcnt(0)" ::: "memory");
    __builtin_amdgcn_s_barrier();
    __builtin_amdgcn_sched_barrier(0);

    for (int kt = 0; kt < HDIM / 64; ++kt) {
        const int cur = kt & 1, nxt = cur ^ 1;
        if (kt + 1 < HDIM / 64) stage(kt + 1, nxt);   // prefetch under compute
#pragma unroll
        for (int kk = 0; kk < 2; ++kk) {
            const int cb = ((quad << 4) | (kk << 6)) ^ swz;
            half8 af[2], bf[2];
#pragma unroll
            for (int mb = 0; mb < 2; ++mb)
                af[mb] = *(const half8*)((const char*)&Ash[cur][wr + mb * 16 + l16][0] + cb);
#pragma unroll
            for (int nb = 0; nb < 2; ++nb)
                bf[nb] = *(const half8*)((const char*)&Bsh[cur][wc + nb * 16 + l16][0] + cb);
#pragma unroll
            for (int mb = 0; mb < 2; ++mb)
#pragma unroll
                for (int nb = 0; nb < 2; ++nb)
                    acc[mb][nb] = __builtin_amdgcn_mfma_f32_16x16x32_f16(af[mb], bf[nb], acc[mb][nb], 0, 0, 0);
        }
        __asm__ volatile("s_waitcnt vmcnt(0)" ::: "memory");  // next tile landed
        __builtin_amdgcn_s_barrier();
        __builtin_amdgcn_sched_barrier(0);
    }

#pragma unroll
    for (int mb = 0; mb < 2; ++mb)
#pragma unroll
        for (int nb = 0; nb < 2; ++nb) {
            int row0 = bm * 64 + wr + mb * 16 + quad * 4;
            int col  = bn * 64 + wc + nb * 16 + l16;
#pragma unroll
            for (int r = 0; r < 4; ++r)
                outF[(size_t)(row0 + r) * HDIM + col] = acc[mb][nb][r];
        }
}

// ---------------- fused attention ----------------
// Reference semantics: softmax over ALL keys, THEN causal zeroing, NO renorm.
// v8: ISSUE-REDUCTION round. Each wave owns TWO 16-row q-groups (16 rows of
// light tile p + 16 rows of heavy tile 15-p): one kf read pair serves both
// groups' QK MFMAs, one vf read serves both groups' PV MFMAs -> LDS reads and
// address VALU per q-row HALVE (r0's amortization on v7's 128-key structure).
// All 8 waves identical work -> no imbalance. Block covers 256 q rows ->
// grid (8,32) = 256 blocks = 1 block/CU (issue-bound, so occupancy loss is
// acceptable; r7 showed barrier cost is minor). XCD-aware remap clusters the
// 8 blocks sharing a head's K/V onto one XCD's L2.
__global__ __launch_bounds__(512, 2)
void attn_fused(const half_t* __restrict__ Qb, const half_t* __restrict__ Kb,
                const half_t* __restrict__ Vtb, half_t* __restrict__ AOut)
{
    // XCD-aware: dispatch xcd = linear%8 = blockIdx.x -> give each x the same
    // 4 heads across all its p-values: bh = (y&3)*8 + x, p = y>>2.
    const int p  = blockIdx.y >> 2;                    // 0..7: q-tile pair (p, 15-p)
    const int bh = (blockIdx.y & 3) * 8 + blockIdx.x;  // 0..31 (b*16+h)
    const int NT = SEQ / 128;    // 16 iterations of 128 keys

    __shared__ __align__(16) half_t Ksh[2][128][64];   // [buf][key][d], 32 KB
    __shared__ __align__(16) half_t Vsh[2][64][128];   // [buf][d][key], 32 KB

    const int t = threadIdx.x;
    const int wave = t >> 6, lane = t & 63, quad = lane >> 4, l16 = lane & 15;
    // group bases: g=0 light tile p, g=1 heavy tile 15-p; 16 rows per group
    const int q0g[2] = { p * 128 + wave * 16, (15 - p) * 128 + wave * 16 };
    const int vtop = 15 - p;    // last V tile needed (128-key units)

    // Q fragments for both groups (B-operand layout of 16x16x32)
    half8 qf0[2], qf1[2];
#pragma unroll
    for (int g = 0; g < 2; ++g) {
        const half_t* Qp = Qb + ((size_t)bh * SEQ + q0g[g] + l16) * DH + quad * 8;
        qf0[g] = *(const half8*)Qp;
        qf1[g] = *(const half8*)(Qp + 32);
    }

    float4v o0[4] = {}, o1[4] = {};   // O^T accum per group
    float4v ls0 = {}, ls1 = {};       // 4 independent denominator chains per group

    // K DMA staging: wave stages rows wave*16 .. wave*16+15 (two 8-row chunks,
    // XOR chunk swizzle within each 8-row group)
    const int krow = lane >> 3, kpos = lane & 7;
    const int kchunk = kpos ^ krow;
    const half_t* Ksrc = Kb + ((size_t)bh * SEQ + wave * 16 + krow) * DH + kchunk * 8;
    const int ko1 = ((quad ^ (l16 & 7)) * 8);
    const int ko2 = ko1 ^ 32;

    // V staging: 512 threads x 2 uint4 = 64 x 128 tile; 16-chunk XOR swizzle
    const int sr  = t >> 3;          // d: 0..63
    const int sc0 = t & 7;           // chunks sc0 and sc0+8 (8 halfs each)
    const half_t* Vg = Vtb + ((size_t)bh * DH + sr) * SEQ + sc0 * 8;
    const int vso0 = ((sc0    ) ^ (sr & 15)) * 8;   // swizzled store offsets (halfs)
    const int vso1 = ((sc0 + 8) ^ (sr & 15)) * 8;

    // ---- prologue: stage K(0), V(0) ----
    {
        uint4 va0 = *(const uint4*)(Vg);
        uint4 va1 = *(const uint4*)(Vg + 64);
        glds16(Ksrc,          &Ksh[0][wave * 16][0]);
        glds16(Ksrc + 8 * DH, &Ksh[0][wave * 16 + 8][0]);
        *(uint4*)&Vsh[0][sr][vso0] = va0;
        *(uint4*)&Vsh[0][sr][vso1] = va1;
    }
    __asm__ volatile("s_waitcnt vmcnt(0)" ::: "memory");
    __asm__ volatile("s_waitcnt lgkmcnt(0)" ::: "memory");
    __builtin_amdgcn_s_barrier();
    __builtin_amdgcn_sched_barrier(0);

    for (int T = 0; T < NT; ++T) {
        const int cur = T & 1, nxt = cur ^ 1;
        const bool kn = (T + 1 < NT);
        const bool vn = kn && (T + 1 <= vtop);

        uint4 va0, va1;
        if (vn) {                         // issue-early
            va0 = *(const uint4*)(Vg + (T + 1) * 128);
            va1 = *(const uint4*)(Vg + (T + 1) * 128 + 64);
        }
        if (kn) {
            const half_t* Kn = Ksrc + (size_t)(T + 1) * 128 * DH;
            glds16(Kn,          &Ksh[nxt][wave * 16][0]);
            glds16(Kn + 8 * DH, &Ksh[nxt][wave * 16 + 8][0]);
        }

#pragma unroll
        for (int hh = 0; hh < 2; ++hh) {
            // S^T = K * Q^T: one kf pair serves BOTH q-groups
            float4v s0[4], s1[4];
            __builtin_amdgcn_s_setprio(1);
#pragma unroll
            for (int nb = 0; nb < 4; ++nb) {
                const half_t* kp = &Ksh[cur][hh * 64 + nb * 16 + l16][0];
                half8 kf0 = *(const half8*)(kp + ko1);
                half8 kf1 = *(const half8*)(kp + ko2);
                float4v a = {};
                a = __builtin_amdgcn_mfma_f32_16x16x32_f16(kf0, qf0[0], a, 0, 0, 0);
                a = __builtin_amdgcn_mfma_f32_16x16x32_f16(kf1, qf1[0], a, 0, 0, 0);
                s0[nb] = a;
                float4v b = {};
                b = __builtin_amdgcn_mfma_f32_16x16x32_f16(kf0, qf0[1], b, 0, 0, 0);
                b = __builtin_amdgcn_mfma_f32_16x16x32_f16(kf1, qf1[1], b, 0, 0, 0);
                s1[nb] = b;
            }
            __builtin_amdgcn_s_setprio(0);

            // P = exp2; 4 independent partial-denominator chains per group
#pragma unroll
            for (int nb = 0; nb < 4; ++nb)
#pragma unroll
                for (int r = 0; r < 4; ++r) {
                    float e0 = __builtin_amdgcn_exp2f(s0[nb][r]);
                    float e1 = __builtin_amdgcn_exp2f(s1[nb][r]);
                    s0[nb][r] = e0; ls0[r] += e0;
                    s1[nb][r] = e1; ls1[r] += e1;
                }

            const int kbase = T * 128 + hh * 64;
            const bool act0 = (kbase <= q0g[0] + 15);   // wave-uniform
            const bool act1 = (kbase <= q0g[1] + 15);   // act1 implies >= act0
            if (act1) {
                // straddle masking (post-softmax zeroing)
                if (kbase + 63 > q0g[1]) {
                    int qg = q0g[1] + l16;
#pragma unroll
                    for (int nb = 0; nb < 4; ++nb)
#pragma unroll
                        for (int r = 0; r < 4; ++r)
                            if (kbase + nb * 16 + quad * 4 + r > qg) s1[nb][r] = 0.f;
                }
                if (act0 && kbase + 63 > q0g[0]) {
                    int qg = q0g[0] + l16;
#pragma unroll
                    for (int nb = 0; nb < 4; ++nb)
#pragma unroll
                        for (int r = 0; r < 4; ++r)
                            if (kbase + nb * 16 + quad * 4 + r > qg) s0[nb][r] = 0.f;
                }
                half4 pf1[4], pf0[4];
#pragma unroll
                for (int nb = 0; nb < 4; ++nb) {
                    union { fp16x2 v2[2]; half4 v4; } u;
                    u.v2[0] = __builtin_amdgcn_cvt_pkrtz(s1[nb][0], s1[nb][1]);
                    u.v2[1] = __builtin_amdgcn_cvt_pkrtz(s1[nb][2], s1[nb][3]);
                    pf1[nb] = u.v4;
                }
                if (act0) {
#pragma unroll
                    for (int nb = 0; nb < 4; ++nb) {
                        union { fp16x2 v2[2]; half4 v4; } u;
                        u.v2[0] = __builtin_amdgcn_cvt_pkrtz(s0[nb][0], s0[nb][1]);
                        u.v2[1] = __builtin_amdgcn_cvt_pkrtz(s0[nb][2], s0[nb][3]);
                        pf0[nb] = u.v4;
                    }
                }
                // one vf read feeds BOTH groups' PV MFMAs
                __builtin_amdgcn_s_setprio(1);
                if (act0) {
#pragma unroll
                    for (int md = 0; md < 4; ++md) {
                        const char* vrow = (const char*)&Vsh[cur][md * 16 + l16][0];
#pragma unroll
                        for (int nb = 0; nb < 4; ++nb) {
                            const int chunk = (hh * 8 + nb * 2 + (quad >> 1)) ^ l16;
                            half4 vf = *(const half4*)(vrow + chunk * 16 + (quad & 1) * 8);
                            o1[md] = __builtin_amdgcn_mfma_f32_16x16x16f16(vf, pf1[nb], o1[md], 0, 0, 0);
                            o0[md] = __builtin_amdgcn_mfma_f32_16x16x16f16(vf, pf0[nb], o0[md], 0, 0, 0);
                        }
                    }
                } else {
#pragma unroll
                    for (int md = 0; md < 4; ++md) {
                        const char* vrow = (const char*)&Vsh[cur][md * 16 + l16][0];
#pragma unroll
                        for (int nb = 0; nb < 4; ++nb) {
                            const int chunk = (hh * 8 + nb * 2 + (quad >> 1)) ^ l16;
                            half4 vf = *(const half4*)(vrow + chunk * 16 + (quad & 1) * 8);
                            o1[md] = __builtin_amdgcn_mfma_f32_16x16x16f16(vf, pf1[nb], o1[md], 0, 0, 0);
                        }
                    }
                }
                __builtin_amdgcn_s_setprio(0);
            }
        }

        if (vn) {                         // write-late into the other buffer
            *(uint4*)&Vsh[nxt][sr][vso0] = va0;
            *(uint4*)&Vsh[nxt][sr][vso1] = va1;
        }
        __asm__ volatile("s_waitcnt vmcnt(0)" ::: "memory");
        __asm__ volatile("s_waitcnt lgkmcnt(0)" ::: "memory");
        __builtin_amdgcn_s_barrier();
        __builtin_amdgcn_sched_barrier(0);
    }

    // epilogue: per group, denominator (2 shuffles) + O^T transpose via LDS.
    const int b = bh >> 4, h = bh & 15;
    const int orow = lane >> 2, occ = (lane & 3) * 16;
    half_t* scr = (half_t*)Ksh + wave * 1152;   // 8 waves x 2304 B within Ksh
    half_t (*Osh)[72] = (half_t(*)[72])scr;     // 16 x 72
#pragma unroll
    for (int g = 0; g < 2; ++g) {
        const float4v& lsg = g ? ls1 : ls0;
        float rs = (lsg[0] + lsg[1]) + (lsg[2] + lsg[3]);
        rs += __shfl_xor(rs, 16, 64);
        rs += __shfl_xor(rs, 32, 64);
        const float inv = 1.0f / rs;
#pragma unroll
        for (int md = 0; md < 4; ++md)
#pragma unroll
            for (int r = 0; r < 4; ++r)
                Osh[l16][md * 16 + quad * 4 + r] =
                    (half_t)(((g ? o1 : o0)[md][r]) * inv);
        __asm__ volatile("s_waitcnt lgkmcnt(0)" ::: "memory");
        uint4 v0 = *(const uint4*)&Osh[orow][occ];
        uint4 v1 = *(const uint4*)&Osh[orow][occ + 8];
        const int s = q0g[g] + orow;
        half_t* dst = AOut + ((size_t)(b * SEQ + s)) * HDIM + h * DH + occ;
        *(uint4*)dst       = v0;
        *(uint4*)(dst + 8) = v1;
    }
}

// ---------------- launch ----------------
extern "C" void kernel_launch(void* const* d_in, const int* in_sizes, int n_in,
                              void* d_out, int out_size, void* d_ws, size_t ws_size,
                              hipStream_t stream)
{
    const float* x  = (const float*)d_in[0];
    const float* wq = (const float*)d_in[1];
    const float* wk = (const float*)d_in[2];
    const float* wv = (const float*)d_in[3];
    const float* wo = (const float*)d_in[4];
    float* out = (float*)d_out;

    char* ws = (char*)d_ws;
    size_t off = 0;
    auto alloc = [&](size_t bytes) -> void* {
        void* p = ws + off;
        off += (bytes + 255) & ~(size_t)255;
        return p;
    };
    half_t* xh   = (half_t*)alloc((size_t)MTOT * HDIM * 2);   // 8 MB
    half_t* wqh  = (half_t*)alloc((size_t)HDIM * HDIM * 2);   // 2 MB
    half_t* wkh  = (half_t*)alloc((size_t)HDIM * HDIM * 2);
    half_t* wvh  = (half_t*)alloc((size_t)HDIM * HDIM * 2);
    half_t* woh  = (half_t*)alloc((size_t)HDIM * HDIM * 2);
    half_t* Qb   = (half_t*)alloc((size_t)BHTOT * SEQ * DH * 2);  // 8 MB
    half_t* Kb   = (half_t*)alloc((size_t)BHTOT * SEQ * DH * 2);
    half_t* Vtb  = (half_t*)alloc((size_t)BHTOT * SEQ * DH * 2);
    half_t* ah   = (half_t*)alloc((size_t)MTOT * HDIM * 2);       // 8 MB
    float2* rope = (float2*)alloc((size_t)SEQ * 32 * sizeof(float2));

    prep<<<8448, 256, 0, stream>>>(x, wq, wk, wv, wo, xh, wqh, wkh, wvh, woh, rope);

    // Q, K, V in one launch (grid.z selects weight + epilogue)
    gemm_qkv<<<dim3(32, 8, 3), 256, 0, stream>>>(xh, wqh, wkh, wvh,
                                                 Qb, Kb, Vtb, rope);
    // attn: 512-thread blocks, 256 blocks = 1 block/CU, 2 q-groups/wave
    attn_fused<<<dim3(8, 32), 512, 0, stream>>>(Qb, Kb, Vtb, ah);
    // out = attn @ w_o^T: 64x64 tiles, 1024 blocks = 4 blocks/CU, 2-phase
    gemm_out<<<dim3(64, 16), 256, 0, stream>>>(ah, woh, out);
}

// Round 9
// 180.470 us; speedup vs baseline: 1.0341x; 1.0318x over previous
//
#include <hip/hip_runtime.h>
#include <math.h>

#define SEQ   2048
#define HDIM  1024
#define NH    16
#define DH    64
#define MTOT  4096   // B*S
#define BHTOT 32     // B*NH

typedef _Float16 half_t;
typedef __attribute__((ext_vector_type(2))) __fp16 fp16x2;
typedef __attribute__((ext_vector_type(4))) _Float16 half4;
typedef __attribute__((ext_vector_type(8))) _Float16 half8;
typedef __attribute__((ext_vector_type(4))) float float4v;

// async global->LDS DMA, 16 B per lane; LDS dest = wave-uniform base + lane*16
typedef __attribute__((address_space(1))) const unsigned int guint;
typedef __attribute__((address_space(3))) unsigned int luint;
__device__ __forceinline__ void glds16(const half_t* g, half_t* l) {
    __builtin_amdgcn_global_load_lds((guint*)g, (luint*)l, 16, 0, 0);
}

// ---------------- fused prologue: 5 fp32->fp16 casts + rope table ----------------
__global__ __launch_bounds__(256)
void prep(const float* __restrict__ x,  const float* __restrict__ wq,
          const float* __restrict__ wk, const float* __restrict__ wv,
          const float* __restrict__ wo,
          half_t* __restrict__ xh,  half_t* __restrict__ wqh,
          half_t* __restrict__ wkh, half_t* __restrict__ wvh,
          half_t* __restrict__ woh, float2* __restrict__ rope)
{
    const int bid = blockIdx.x;
    if (bid < 8192) {
        int i = bid * 256 + threadIdx.x;
        const float* s; half_t* d;
        if (i < 1048576) { s = x; d = xh; }
        else {
            int j = i - 1048576;
            int w = j >> 18; i = j & 262143;
            s = (w == 0) ? wq : (w == 1) ? wk : (w == 2) ? wv : wo;
            d = (w == 0) ? wqh : (w == 1) ? wkh : (w == 2) ? wvh : woh;
        }
        float4 v = ((const float4*)s)[i];
        union { half_t h[4]; uint2 u; } tmp;
        tmp.h[0] = (half_t)v.x; tmp.h[1] = (half_t)v.y;
        tmp.h[2] = (half_t)v.z; tmp.h[3] = (half_t)v.w;
        ((uint2*)d)[i] = tmp.u;
    } else {
        int tt = (bid - 8192) * 256 + threadIdx.x;   // 0 .. SEQ*32-1
        int s = tt >> 5, j = tt & 31;
        float inv = powf(10000.0f, -(float)j / 32.0f);
        float ang = (float)s * inv;
        rope[tt] = make_float2(cosf(ang), sinf(ang));
    }
}

// ---------------- GEMM: QKV only. C = A(4096x1024,f16) * W^T, 128x128 tiles ----
// v5: BK=32 + DOUBLE-BUFFER 2-phase (T3-minimal): stage(t+1) is issued BEFORE
// compute(t), so DMA latency hides under the 16 MFMAs + other waves; the
// single vmcnt(0)+barrier at iter end waits only the residue. LDS stays 32 KB
// (2 x 8 KB per operand) -> same 3-blocks/CU residency as the single-buffer
// version (avoids the m132 64KB-occupancy trap). Line-local XOR swizzle
// (chunk ^ (row&3) within the 64-B row) kept: DMA source line-complete,
// fragment reads at structural bank minimum.
// mode 0: Qb (RoPE+scale), 1: Kb (RoPE), 2: Vtb (T).
__global__ __launch_bounds__(256, 5)
void gemm_qkv(const half_t* __restrict__ A,
              const half_t* __restrict__ w0, const half_t* __restrict__ w1,
              const half_t* __restrict__ w2,
              half_t* __restrict__ Qb, half_t* __restrict__ Kb,
              half_t* __restrict__ Vtb,
              const float2* __restrict__ rope)
{
    const int mode = blockIdx.z;
    const half_t* Bw = (mode == 1) ? w1 : (mode == 2) ? w2 : w0;

    __shared__ __align__(16) half_t Tsh[2][2][128][32];   // [buf][A|B][row][32], 32 KB

    const int t    = threadIdx.x;
    const int lane = t & 63;
    const int wave = t >> 6;
    const int quad = lane >> 4;
    const int l16  = lane & 15;
    const int wr   = (wave >> 1) * 64;
    const int wc   = (wave & 1) * 64;
    const int bm   = blockIdx.x, bn = blockIdx.y;

    // staging: one glds16 covers 16 rows x 64 B; chunk XOR-swizzled by row&3
    const int srow   = lane >> 2;               // 0..15 within a 16-row DMA chunk
    const int schunk = (lane & 3) ^ (srow & 3); // line-local pre-swizzle (16B chunks)
    const half_t* Asrc = A  + (size_t)(bm * 128 + srow) * HDIM + schunk * 8;
    const half_t* Bsrc = Bw + (size_t)(bn * 128 + srow) * HDIM + schunk * 8;
    const int swz = (l16 & 3) << 4;             // read-side XOR (byte offset)

    auto stage = [&](int kt, int buf) {
        const half_t* Ak = Asrc + kt * 32;
        const half_t* Bk = Bsrc + kt * 32;
        glds16(Ak + (size_t)(wave * 32)      * HDIM, &Tsh[buf][0][wave * 32][0]);
        glds16(Ak + (size_t)(wave * 32 + 16) * HDIM, &Tsh[buf][0][wave * 32 + 16][0]);
        glds16(Bk + (size_t)(wave * 32)      * HDIM, &Tsh[buf][1][wave * 32][0]);
        glds16(Bk + (size_t)(wave * 32 + 16) * HDIM, &Tsh[buf][1][wave * 32 + 16][0]);
    };

    float4v acc[4][4] = {};

    stage(0, 0);
    __asm__ volatile("s_waitcnt vmcnt(0)" ::: "memory");
    __builtin_amdgcn_s_barrier();
    __builtin_amdgcn_sched_barrier(0);

    for (int kt = 0; kt < HDIM / 32; ++kt) {
        const int cur = kt & 1, nxt = cur ^ 1;
        if (kt + 1 < HDIM / 32) stage(kt + 1, nxt);   // prefetch under compute
        const int cb = (quad << 4) ^ swz;
        half8 af[4], bf[4];
#pragma unroll
        for (int mb = 0; mb < 4; ++mb)
            af[mb] = *(const half8*)((const char*)&Tsh[cur][0][wr + mb * 16 + l16][0] + cb);
#pragma unroll
        for (int nb = 0; nb < 4; ++nb)
            bf[nb] = *(const half8*)((const char*)&Tsh[cur][1][wc + nb * 16 + l16][0] + cb);
#pragma unroll
        for (int mb = 0; mb < 4; ++mb)
#pragma unroll
            for (int nb = 0; nb < 4; ++nb)
                acc[mb][nb] = __builtin_amdgcn_mfma_f32_16x16x32_f16(af[mb], bf[nb], acc[mb][nb], 0, 0, 0);
        __asm__ volatile("s_waitcnt vmcnt(0)" ::: "memory");  // next tile landed
        __builtin_amdgcn_s_barrier();
        __builtin_amdgcn_sched_barrier(0);
    }

    if (mode == 2) {  // V, transposed store: Vtb[bh][d][s]
#pragma unroll
        for (int mb = 0; mb < 4; ++mb)
#pragma unroll
            for (int nb = 0; nb < 4; ++nb) {
                int row0 = bm * 128 + wr + mb * 16 + quad * 4;
                int col  = bn * 128 + wc + nb * 16 + l16;
                int b = row0 >> 11, s0 = row0 & 2047;
                int h = col >> 6,  dd = col & 63;
                union { half_t h4[4]; uint2 u; } tmp;
#pragma unroll
                for (int r = 0; r < 4; ++r) tmp.h4[r] = (half_t)acc[mb][nb][r];
                *(uint2*)&Vtb[((size_t)((b * NH + h) * DH + dd)) * SEQ + s0] = tmp.u;
            }
        return;
    }
    // mode 0 (Q: rope + scale) / mode 1 (K: rope)
    {
        half_t* Ob = (mode == 0) ? Qb : Kb;
        const float scl = (mode == 0) ? 0.125f * 1.44269504088896f : 1.0f;
        const int h = (bn * 128 + wc) >> 6;   // wave's 64 cols = one head
        // per-wave fp32 bounce [16][68], overlaid on the 32 KB tile LDS
        float* E = (float*)&Tsh[0][0][0][0] + wave * 1088;
#pragma unroll
        for (int mb = 0; mb < 4; ++mb) {
#pragma unroll
            for (int nb = 0; nb < 4; ++nb)
#pragma unroll
                for (int r = 0; r < 4; ++r)
                    E[(quad * 4 + r) * 68 + nb * 16 + l16] = acc[mb][nb][r];
            __asm__ volatile("s_waitcnt lgkmcnt(0)" ::: "memory");  // wave-private region
#pragma unroll
            for (int c = 0; c < 2; ++c) {
                const int uidx = c * 64 + lane;
                const int row = uidx >> 3, ch = uidx & 7;
                const int sg = bm * 128 + wr + mb * 16 + row;
                const int b = sg >> 11, s = sg & 2047;
                const float* Er = E + row * 68 + ch * 8;
                const float4 e0 = *(const float4*)Er;
                const float4 e1 = *(const float4*)(Er + 4);
                const float4* rp = (const float4*)(rope + (size_t)s * 32 + ch * 4);
                const float4 r01 = rp[0];   // cos0,sin0,cos1,sin1
                const float4 r23 = rp[1];
                union { half_t hh[8]; uint4 u; } o;
                o.hh[0] = (half_t)((e0.x * r01.x - e0.y * r01.y) * scl);
                o.hh[1] = (half_t)((e0.x * r01.y + e0.y * r01.x) * scl);
                o.hh[2] = (half_t)((e0.z * r01.z - e0.w * r01.w) * scl);
                o.hh[3] = (half_t)((e0.z * r01.w + e0.w * r01.z) * scl);
                o.hh[4] = (half_t)((e1.x * r23.x - e1.y * r23.y) * scl);
                o.hh[5] = (half_t)((e1.x * r23.y + e1.y * r23.x) * scl);
                o.hh[6] = (half_t)((e1.z * r23.z - e1.w * r23.w) * scl);
                o.hh[7] = (half_t)((e1.z * r23.w + e1.w * r23.z) * scl);
                *(uint4*)&Ob[((size_t)((b * NH + h) * SEQ + s)) * DH + ch * 8] = o.u;
            }
            // per-wave DS ops are in-order: reads above complete before next mb's writes
        }
    }
}

// ---------------- output GEMM: out(f32) = ah(4096x1024,f16) @ wo^T ----------------
// 64x64 tiles -> grid (64,16) = 1024 blocks = 4 blocks/CU, 2-phase prefetch.
__global__ __launch_bounds__(256)
void gemm_out(const half_t* __restrict__ A, const half_t* __restrict__ W,
              float* __restrict__ outF)
{
    __shared__ __align__(16) half_t Ash[2][64][64];    // 16 KB
    __shared__ __align__(16) half_t Bsh[2][64][64];    // 16 KB

    const int t    = threadIdx.x;
    const int lane = t & 63;
    const int wave = t >> 6;
    const int quad = lane >> 4;
    const int l16  = lane & 15;
    const int wr   = (wave >> 1) * 32;   // M offset within tile
    const int wc   = (wave & 1) * 32;    // N offset
    const int bm   = blockIdx.x, bn = blockIdx.y;

    const int srow   = lane >> 3;
    const int schunk = (lane & 7) ^ (srow & 3);
    const half_t* Asrc = A + (size_t)(bm * 64 + srow) * HDIM + schunk * 8;
    const half_t* Bsrc = W + (size_t)(bn * 64 + srow) * HDIM + schunk * 8;
    const int swz = (l16 & 3) << 4;

    auto stage = [&](int kt, int buf) {
        const half_t* Ak = Asrc + kt * 64;
        const half_t* Bk = Bsrc + kt * 64;
#pragma unroll
        for (int c = 0; c < 2; ++c) {
            const int r8 = wave * 16 + c * 8;
            glds16(Ak + (size_t)r8 * HDIM, &Ash[buf][r8][0]);
            glds16(Bk + (size_t)r8 * HDIM, &Bsh[buf][r8][0]);
        }
    };

    float4v acc[2][2] = {};

    stage(0, 0);
    __asm__ volatile("s_waitcnt vmcnt(0)" ::: "memory");
    __builtin_amdgcn_s_barrier();
    __builtin_amdgcn_sched_barrier(0);

    for (int kt = 0; kt < HDIM / 64; ++kt) {
        const int cur = kt & 1, nxt = cur ^ 1;
        if (kt + 1 < HDIM / 64) stage(kt + 1, nxt);   // prefetch under compute
#pragma unroll
        for (int kk = 0; kk < 2; ++kk) {
            const int cb = ((quad << 4) | (kk << 6)) ^ swz;
            half8 af[2], bf[2];
#pragma unroll
            for (int mb = 0; mb < 2; ++mb)
                af[mb] = *(const half8*)((const char*)&Ash[cur][wr + mb * 16 + l16][0] + cb);
#pragma unroll
            for (int nb = 0; nb < 2; ++nb)
                bf[nb] = *(const half8*)((const char*)&Bsh[cur][wc + nb * 16 + l16][0] + cb);
#pragma unroll
            for (int mb = 0; mb < 2; ++mb)
#pragma unroll
                for (int nb = 0; nb < 2; ++nb)
                    acc[mb][nb] = __builtin_amdgcn_mfma_f32_16x16x32_f16(af[mb], bf[nb], acc[mb][nb], 0, 0, 0);
        }
        __asm__ volatile("s_waitcnt vmcnt(0)" ::: "memory");  // next tile landed
        __builtin_amdgcn_s_barrier();
        __builtin_amdgcn_sched_barrier(0);
    }

#pragma unroll
    for (int mb = 0; mb < 2; ++mb)
#pragma unroll
        for (int nb = 0; nb < 2; ++nb) {
            int row0 = bm * 64 + wr + mb * 16 + quad * 4;
            int col  = bn * 64 + wc + nb * 16 + l16;
#pragma unroll
            for (int r = 0; r < 4; ++r)
                outF[(size_t)(row0 + r) * HDIM + col] = acc[mb][nb][r];
        }
}

// ---------------- fused attention ----------------
// Reference semantics: softmax over ALL keys, THEN causal zeroing, NO renorm.
// v7 (reverted to r7's best-measured 49.8 µs version): 128-key iterations,
// Ksh/Vsh double-buffered (64 KB, 2 blocks/CU = 16 waves/CU). Per iteration:
// stage K(T+1) + V(T+1) (issue-early/write-late), two independent 64-key
// half-chains {QK->exp->cvt->PV} for intra-iteration ILP between barriers.
__global__ __launch_bounds__(512, 4)
void attn_fused(const half_t* __restrict__ Qb, const half_t* __restrict__ Kb,
                const half_t* __restrict__ Vtb, half_t* __restrict__ AOut)
{
    const int bx = blockIdx.x;   // 0..15
    const int p  = bx >> 1;      // q-tile pair (p, 15-p), p in 0..7
    const int hf = bx & 1;       // which 64-row half of each tile
    const int bh = blockIdx.y;   // 0..31 (b*16+h)
    const int NT = SEQ / 128;    // 16 iterations of 128 keys

    __shared__ __align__(16) half_t Ksh[2][128][64];   // [buf][key][d], 32 KB
    __shared__ __align__(16) half_t Vsh[2][64][128];   // [buf][d][key], 32 KB

    const int t = threadIdx.x;
    const int wave = t >> 6, lane = t & 63, quad = lane >> 4, l16 = lane & 15;
    const int heavy = wave >> 2, wl = wave & 3;
    const int qtile = heavy ? (15 - p) : p;
    const int q0 = qtile * 128 + hf * 64 + wl * 16;   // wave's 16 q rows
    const int vtop = 15 - p;    // last V tile needed by this block (128-key units)

    // Q fragment (B-operand layout of 16x16x32)
    const half_t* Qp = Qb + ((size_t)bh * SEQ + q0 + l16) * DH + quad * 8;
    const half8 qf0 = *(const half8*)Qp;
    const half8 qf1 = *(const half8*)(Qp + 32);

    float4v o[4] = {};     // O^T accum
    float4v ls = {};       // 4 independent denominator chains

    // K DMA staging: wave stages rows wave*16 .. wave*16+15 (two 8-row chunks,
    // XOR chunk swizzle within each 8-row group)
    const int krow = lane >> 3, kpos = lane & 7;
    const int kchunk = kpos ^ krow;
    const half_t* Ksrc = Kb + ((size_t)bh * SEQ + wave * 16 + krow) * DH + kchunk * 8;
    const int ko1 = ((quad ^ (l16 & 7)) * 8);
    const int ko2 = ko1 ^ 32;

    // V staging: 512 threads x 2 uint4 = 64 x 128 tile; 16-chunk XOR swizzle
    const int sr  = t >> 3;          // d: 0..63
    const int sc0 = t & 7;           // chunks sc0 and sc0+8 (8 halfs each)
    const half_t* Vg = Vtb + ((size_t)bh * DH + sr) * SEQ + sc0 * 8;
    const int vso0 = ((sc0    ) ^ (sr & 15)) * 8;   // swizzled store offsets (halfs)
    const int vso1 = ((sc0 + 8) ^ (sr & 15)) * 8;

    // ---- prologue: stage K(0), V(0) ----
    {
        uint4 va0 = *(const uint4*)(Vg);
        uint4 va1 = *(const uint4*)(Vg + 64);
        glds16(Ksrc,          &Ksh[0][wave * 16][0]);
        glds16(Ksrc + 8 * DH, &Ksh[0][wave * 16 + 8][0]);
        *(uint4*)&Vsh[0][sr][vso0] = va0;
        *(uint4*)&Vsh[0][sr][vso1] = va1;
    }
    __asm__ volatile("s_waitcnt vmcnt(0)" ::: "memory");
    __asm__ volatile("s_waitcnt lgkmcnt(0)" ::: "memory");
    __builtin_amdgcn_s_barrier();
    __builtin_amdgcn_sched_barrier(0);

    for (int T = 0; T < NT; ++T) {
        const int cur = T & 1, nxt = cur ^ 1;
        const bool kn = (T + 1 < NT);
        const bool vn = kn && (T + 1 <= vtop);

        uint4 va0, va1;
        if (vn) {                         // issue-early
            va0 = *(const uint4*)(Vg + (T + 1) * 128);
            va1 = *(const uint4*)(Vg + (T + 1) * 128 + 64);
        }
        if (kn) {
            const half_t* Kn = Ksrc + (size_t)(T + 1) * 128 * DH;
            glds16(Kn,          &Ksh[nxt][wave * 16][0]);
            glds16(Kn + 8 * DH, &Ksh[nxt][wave * 16 + 8][0]);
        }

#pragma unroll
        for (int hh = 0; hh < 2; ++hh) {
            // S^T = K * Q^T over this 64-key half
            float4v sc[4];
            __builtin_amdgcn_s_setprio(1);
#pragma unroll
            for (int nb = 0; nb < 4; ++nb) {
                const half_t* kp = &Ksh[cur][hh * 64 + nb * 16 + l16][0];
                half8 kf0 = *(const half8*)(kp + ko1);
                half8 kf1 = *(const half8*)(kp + ko2);
                float4v a = {};
                a = __builtin_amdgcn_mfma_f32_16x16x32_f16(kf0, qf0, a, 0, 0, 0);
                a = __builtin_amdgcn_mfma_f32_16x16x32_f16(kf1, qf1, a, 0, 0, 0);
                sc[nb] = a;
            }
            __builtin_amdgcn_s_setprio(0);

            // P = exp2(sc); 4 independent partial-denominator chains
#pragma unroll
            for (int nb = 0; nb < 4; ++nb)
#pragma unroll
                for (int r = 0; r < 4; ++r) {
                    float e = __builtin_amdgcn_exp2f(sc[nb][r]);
                    sc[nb][r] = e;
                    ls[r] += e;
                }

            const int kbase = T * 128 + hh * 64;
            if (kbase <= q0 + 15) {   // wave-uniform: at least one unmasked key
                if (kbase + 63 > q0) {   // straddle: post-softmax zeroing
                    int qg = q0 + l16;
#pragma unroll
                    for (int nb = 0; nb < 4; ++nb)
#pragma unroll
                        for (int r = 0; r < 4; ++r)
                            if (kbase + nb * 16 + quad * 4 + r > qg) sc[nb][r] = 0.f;
                }
                half4 pf[4];
#pragma unroll
                for (int nb = 0; nb < 4; ++nb) {
                    union { fp16x2 v2[2]; half4 v4; } u;
                    u.v2[0] = __builtin_amdgcn_cvt_pkrtz(sc[nb][0], sc[nb][1]);
                    u.v2[1] = __builtin_amdgcn_cvt_pkrtz(sc[nb][2], sc[nb][3]);
                    pf[nb] = u.v4;
                }
                __builtin_amdgcn_s_setprio(1);
#pragma unroll
                for (int md = 0; md < 4; ++md) {
                    const char* vrow = (const char*)&Vsh[cur][md * 16 + l16][0];
#pragma unroll
                    for (int nb = 0; nb < 4; ++nb) {
                        const int chunk = (hh * 8 + nb * 2 + (quad >> 1)) ^ l16;
                        half4 vf = *(const half4*)(vrow + chunk * 16 + (quad & 1) * 8);
                        o[md] = __builtin_amdgcn_mfma_f32_16x16x16f16(vf, pf[nb], o[md], 0, 0, 0);
                    }
                }
                __builtin_amdgcn_s_setprio(0);
            }
        }

        if (vn) {                         // write-late into the other buffer
            *(uint4*)&Vsh[nxt][sr][vso0] = va0;
            *(uint4*)&Vsh[nxt][sr][vso1] = va1;
        }
        __asm__ volatile("s_waitcnt vmcnt(0)" ::: "memory");
        __asm__ volatile("s_waitcnt lgkmcnt(0)" ::: "memory");
        __builtin_amdgcn_s_barrier();
        __builtin_amdgcn_sched_barrier(0);
    }

    // epilogue: denominator (2 shuffles) + O^T transpose via per-wave LDS scratch.
    const int b = bh >> 4, h = bh & 15;
    const int orow = lane >> 2, occ = (lane & 3) * 16;
    half_t* scr = (heavy ? (half_t*)Vsh : (half_t*)Ksh) + wl * 1152;
    half_t (*Osh)[72] = (half_t(*)[72])scr;   // 16 x 72
    {
        float rs = (ls[0] + ls[1]) + (ls[2] + ls[3]);
        rs += __shfl_xor(rs, 16, 64);
        rs += __shfl_xor(rs, 32, 64);
        const float inv = 1.0f / rs;
#pragma unroll
        for (int md = 0; md < 4; ++md)
#pragma unroll
            for (int r = 0; r < 4; ++r)
                Osh[l16][md * 16 + quad * 4 + r] = (half_t)(o[md][r] * inv);
        __asm__ volatile("s_waitcnt lgkmcnt(0)" ::: "memory");
        uint4 o0 = *(const uint4*)&Osh[orow][occ];
        uint4 o1 = *(const uint4*)&Osh[orow][occ + 8];
        const int s = q0 + orow;
        half_t* dst = AOut + ((size_t)(b * SEQ + s)) * HDIM + h * DH + occ;
        *(uint4*)dst       = o0;
        *(uint4*)(dst + 8) = o1;
    }
}

// ---------------- launch ----------------
extern "C" void kernel_launch(void* const* d_in, const int* in_sizes, int n_in,
                              void* d_out, int out_size, void* d_ws, size_t ws_size,
                              hipStream_t stream)
{
    const float* x  = (const float*)d_in[0];
    const float* wq = (const float*)d_in[1];
    const float* wk = (const float*)d_in[2];
    const float* wv = (const float*)d_in[3];
    const float* wo = (const float*)d_in[4];
    float* out = (float*)d_out;

    char* ws = (char*)d_ws;
    size_t off = 0;
    auto alloc = [&](size_t bytes) -> void* {
        void* p = ws + off;
        off += (bytes + 255) & ~(size_t)255;
        return p;
    };
    half_t* xh   = (half_t*)alloc((size_t)MTOT * HDIM * 2);   // 8 MB
    half_t* wqh  = (half_t*)alloc((size_t)HDIM * HDIM * 2);   // 2 MB
    half_t* wkh  = (half_t*)alloc((size_t)HDIM * HDIM * 2);
    half_t* wvh  = (half_t*)alloc((size_t)HDIM * HDIM * 2);
    half_t* woh  = (half_t*)alloc((size_t)HDIM * HDIM * 2);
    half_t* Qb   = (half_t*)alloc((size_t)BHTOT * SEQ * DH * 2);  // 8 MB
    half_t* Kb   = (half_t*)alloc((size_t)BHTOT * SEQ * DH * 2);
    half_t* Vtb  = (half_t*)alloc((size_t)BHTOT * SEQ * DH * 2);
    half_t* ah   = (half_t*)alloc((size_t)MTOT * HDIM * 2);       // 8 MB
    float2* rope = (float2*)alloc((size_t)SEQ * 32 * sizeof(float2));

    prep<<<8448, 256, 0, stream>>>(x, wq, wk, wv, wo, xh, wqh, wkh, wvh, woh, rope);

    // Q, K, V in one launch (grid.z selects weight + epilogue)
    gemm_qkv<<<dim3(32, 8, 3), 256, 0, stream>>>(xh, wqh, wkh, wvh,
                                                 Qb, Kb, Vtb, rope);
    // attn: 512-thread blocks, 512 blocks = 2 blocks/CU, 128-key iterations
    attn_fused<<<dim3(16, 32), 512, 0, stream>>>(Qb, Kb, Vtb, ah);
    // out = attn @ w_o^T: 64x64 tiles, 1024 blocks = 4 blocks/CU, 2-phase
    gemm_out<<<dim3(64, 16), 256, 0, stream>>>(ah, woh, out);
}